// Round 10
// baseline (610.234 us; speedup 1.0000x reference)
//
#include <hip/hip_runtime.h>
#include <math.h>

#define NN 2048
#define NE 65536
#define HID 128

typedef unsigned int uint_t;
typedef unsigned short ushort_t;
typedef __attribute__((ext_vector_type(8))) short bf16x8;
typedef __attribute__((ext_vector_type(4))) float f32x4;

__device__ __forceinline__ ushort_t bf16_rne(float f) {
  uint_t u = __float_as_uint(f);
  return (ushort_t)((u + 0x7fffu + ((u >> 16) & 1u)) >> 16);
}
__device__ __forceinline__ float bf16_f(ushort_t h) {
  return __uint_as_float(((uint_t)h) << 16);
}

// ---------------------------------------------------------------------------
// Encoder weight prep (validated r5): We2 -> MFMA B-frags, bf16 hi/lo.
// ---------------------------------------------------------------------------
__global__ void wprep_kernel(const float* __restrict__ We2, ushort_t* __restrict__ Wb) {
  int idx = blockIdx.x*256 + threadIdx.x;          // over (s,nt,l,j) = 24*13*64*8
  if (idx >= 24*13*64*8) return;
  int j = idx & 7;
  int l = (idx >> 3) & 63;
  int t = idx >> 9;                                // s*13 + nt
  int s = t / 13, nt = t - s*13;
  int oc = nt*16 + (l & 15);
  int ic = (s & 3)*32 + (l >> 4)*8 + j;
  int tap = s >> 2, kh = tap >> 1, kw = tap & 1;
  float wv = (oc < 200 && ic < 100) ? We2[((oc*100 + ic)*3 + kh)*2 + kw] : 0.f;
  ushort_t hi = bf16_rne(wv);
  float lo = wv - bf16_f(hi);
  Wb[t*1024 + l*8 + j]       = hi;
  Wb[t*1024 + 512 + l*8 + j] = bf16_rne(lo);
}

// ---------------------------------------------------------------------------
// Generic GEMM weight prep (validated r7)
// ---------------------------------------------------------------------------
struct WDesc {
  const float* s0; const float* s1;
  int K0; int K; int N; int NT; int tileStart;
};
struct WPack { WDesc d[8]; };

__global__ __launch_bounds__(256) void wprep_gemm_kernel(WPack p, ushort_t* __restrict__ Wg) {
  int b = blockIdx.x;
  int g = 0;
  while (g < 7 && b >= p.d[g+1].tileStart) ++g;
  const WDesc& d = p.d[g];
  int t = b - d.tileStart;
  int s = t / d.NT, nt = t - s*d.NT;
  size_t base = (size_t)b * 1024;
#pragma unroll
  for (int u = 0; u < 2; ++u) {
    int pos = threadIdx.x*2 + u;          // 0..511
    int l = pos >> 3, j = pos & 7;
    int k = s*32 + (l >> 4)*8 + j;
    int n = nt*16 + (l & 15);
    float wv = 0.f;
    if (k < d.K && n < d.N)
      wv = (k < d.K0) ? d.s0[k*d.N + n] : d.s1[(k - d.K0)*d.N + n];
    ushort_t hi = bf16_rne(wv);
    float lo = wv - bf16_f(hi);
    Wg[base + pos]       = hi;
    Wg[base + 512 + pos] = bf16_rne(lo);
  }
}

// ---------------------------------------------------------------------------
// Fused encoder v5: v4 + MFMA dependency-distance fix — per K-step, issue all
// 36 independent hi-MFMAs, then all 36 lo-MFMAs (per-acc order unchanged:
// hi before lo -> bit-exact vs v4; dependent-issue distance 1 -> >=33).
// ---------------------------------------------------------------------------
#define H1_USHORTS (294*104 + 64)
#define H2STRIDE 114

__global__ __launch_bounds__(256, 2) void encoder_kernel(
    const float* __restrict__ inputs,
    const float* __restrict__ We1, const float* __restrict__ be1,
    const ushort_t* __restrict__ Wb, const float* __restrict__ be2,
    const float* __restrict__ We3, const float* __restrict__ be3,
    ushort_t* __restrict__ x0b)
{
  __shared__ __align__(16) ushort_t h1[H1_USHORTS];
  __shared__ float sm_x[500];
  __shared__ float sm_w1[900];
  __shared__ float sm_b1[100];
  __shared__ float sm_we3[1200];
  __shared__ float s3buf[188];

  const int n   = blockIdx.x;
  const int tid = threadIdx.x;
  const int l   = tid & 63;
  const int wv  = tid >> 6;
  const int lg  = l >> 4;
  const int lc  = l & 15;
  const int ntb = wv*3;          // this wave's N-tile base (tiles ntb..ntb+2)

  // ---- zero h1 + stage params ----
  {
    uint_t* h1u = (uint_t*)h1;
    for (int i = tid; i < H1_USHORTS/2; i += 256) h1u[i] = 0u;
  }
  for (int i = tid; i < 500;  i += 256) sm_x[i]   = inputs[n*500 + i];
  for (int i = tid; i < 900;  i += 256) sm_w1[i]  = We1[i];
  for (int i = tid; i < 1200; i += 256) sm_we3[i] = We3[i];
  if (tid < 100) sm_b1[tid] = be1[tid];
  __syncthreads();

  // ---- conv1 -> leaky -> h1 bf16 [294 rows][104 stride] ----
  for (int i = tid; i < 29400; i += 256) {
    int p = i / 100, oc = i - p*100;
    int h = p / 3,  w  = p - h*3;
    float a = sm_b1[oc];
#pragma unroll
    for (int kh = 0; kh < 3; ++kh)
#pragma unroll
      for (int kw = 0; kw < 3; ++kw)
        a += sm_x[(h + kh)*5 + (w + kw)] * sm_w1[oc*9 + kh*3 + kw];
    a = a > 0.f ? a : 0.01f*a;
    h1[p*104 + oc] = bf16_rne(a);
  }
  __syncthreads();

  // ---- main conv2 GEMM: wave owns N-tiles ntb..ntb+2, ALL 12 M-tiles ----
  int rowb[12];
#pragma unroll
  for (int m = 0; m < 12; ++m) {
    int pos = m*16 + lc;
    rowb[m] = ((pos >> 1)*3 + (pos & 1))*104;
  }
  f32x4 acc[12][3];
#pragma unroll
  for (int nt = 0; nt < 3; ++nt) {
    float b = be2[(ntb + nt)*16 + lc];     // tiles 0..11 -> oc < 192, always real
#pragma unroll
    for (int m = 0; m < 12; ++m) acc[m][nt] = (f32x4){b, b, b, b};
  }

  bf16x8 Bh0[3], Bl0[3], Bh1[3], Bl1[3];
  auto LOADB = [&](bf16x8 (&bh)[3], bf16x8 (&bl)[3], int s) {
    const ushort_t* bp = Wb + (size_t)(s*13 + ntb)*1024 + l*8;
#pragma unroll
    for (int nt = 0; nt < 3; ++nt) {
      bh[nt] = *(const bf16x8*)(bp + nt*1024);
      bl[nt] = *(const bf16x8*)(bp + nt*1024 + 512);
    }
  };
  auto COMP = [&](bf16x8 (&bh)[3], bf16x8 (&bl)[3], int s) {
    int tap = s >> 2;
    int uofs = ((tap >> 1)*3 + (tap & 1))*104 + (s & 3)*32 + lg*8;
    // hi pass: 36 independent MFMAs
#pragma unroll
    for (int m = 0; m < 12; ++m) {
      bf16x8 a = *(const bf16x8*)(h1 + rowb[m] + uofs);
#pragma unroll
      for (int nt = 0; nt < 3; ++nt)
        acc[m][nt] = __builtin_amdgcn_mfma_f32_16x16x32_bf16(a, bh[nt], acc[m][nt], 0, 0, 0);
    }
    // lo pass: dependent on hi pass at distance >= 33
#pragma unroll
    for (int m = 0; m < 12; ++m) {
      bf16x8 a = *(const bf16x8*)(h1 + rowb[m] + uofs);
#pragma unroll
      for (int nt = 0; nt < 3; ++nt)
        acc[m][nt] = __builtin_amdgcn_mfma_f32_16x16x32_bf16(a, bl[nt], acc[m][nt], 0, 0, 0);
    }
  };

  LOADB(Bh0, Bl0, 0);
#pragma unroll 1
  for (int s = 0; s < 24; s += 2) {
    LOADB(Bh1, Bl1, s + 1);
    COMP(Bh0, Bl0, s);
    if (s + 2 < 24) LOADB(Bh0, Bl0, s + 2);
    COMP(Bh1, Bl1, s + 1);
  }

  // ---- tail tile 12 (oc 192..207): M-split by wave, rows wv*48..+47 ----
  int rowb2[3];
#pragma unroll
  for (int m = 0; m < 3; ++m) {
    int pos = wv*48 + m*16 + lc;
    rowb2[m] = ((pos >> 1)*3 + (pos & 1))*104;
  }
  f32x4 acc2[3];
  {
    int oc = 192 + lc;
    float b = (oc < 200) ? be2[oc] : 0.f;
#pragma unroll
    for (int m = 0; m < 3; ++m) acc2[m] = (f32x4){b, b, b, b};
  }
  bf16x8 th0, tl0, th1, tl1;
  auto LOADT = [&](bf16x8& th, bf16x8& tl, int s) {
    const ushort_t* bp = Wb + (size_t)(s*13 + 12)*1024 + l*8;
    th = *(const bf16x8*)(bp);
    tl = *(const bf16x8*)(bp + 512);
  };
  auto COMPT = [&](bf16x8& th, bf16x8& tl, int s) {
    int tap = s >> 2;
    int uofs = ((tap >> 1)*3 + (tap & 1))*104 + (s & 3)*32 + lg*8;
    bf16x8 a0 = *(const bf16x8*)(h1 + rowb2[0] + uofs);
    bf16x8 a1 = *(const bf16x8*)(h1 + rowb2[1] + uofs);
    bf16x8 a2 = *(const bf16x8*)(h1 + rowb2[2] + uofs);
    acc2[0] = __builtin_amdgcn_mfma_f32_16x16x32_bf16(a0, th, acc2[0], 0, 0, 0);
    acc2[1] = __builtin_amdgcn_mfma_f32_16x16x32_bf16(a1, th, acc2[1], 0, 0, 0);
    acc2[2] = __builtin_amdgcn_mfma_f32_16x16x32_bf16(a2, th, acc2[2], 0, 0, 0);
    acc2[0] = __builtin_amdgcn_mfma_f32_16x16x32_bf16(a0, tl, acc2[0], 0, 0, 0);
    acc2[1] = __builtin_amdgcn_mfma_f32_16x16x32_bf16(a1, tl, acc2[1], 0, 0, 0);
    acc2[2] = __builtin_amdgcn_mfma_f32_16x16x32_bf16(a2, tl, acc2[2], 0, 0, 0);
  };
  LOADT(th0, tl0, 0);
#pragma unroll 1
  for (int s = 0; s < 24; s += 2) {
    LOADT(th1, tl1, s + 1);
    COMPT(th0, tl0, s);
    if (s + 2 < 24) LOADT(th0, tl0, s + 2);
    COMPT(th1, tl1, s + 1);
  }

  // ---- leaky(h2) -> LDS (reuse h1) in two oc-halves, conv3 partials ----
  ushort_t* h2s = h1;
  float s3 = 0.f;
#pragma unroll 1
  for (int pass = 0; pass < 2; ++pass) {
    const int ocb = pass ? 112 : 0;
    __syncthreads();   // pass0: all h1 GEMM reads done; pass1: conv3 pass0 reads done
#pragma unroll
    for (int nt = 0; nt < 3; ++nt) {
      int t = ntb + nt;
      bool inc = pass ? (t >= 7) : (t < 7);
      if (inc) {
        int ocl = t*16 + lc - ocb;
#pragma unroll
        for (int m = 0; m < 12; ++m)
#pragma unroll
          for (int r = 0; r < 4; ++r) {
            int pos = m*16 + lg*4 + r;
            float v = acc[m][nt][r];
            v = v > 0.f ? v : 0.01f*v;
            h2s[pos*H2STRIDE + ocl] = bf16_rne(v);
          }
      }
    }
    if (pass == 1) {
      int ocl = 80 + lc;   // oc = 192+lc, minus ocb=112
#pragma unroll
      for (int m = 0; m < 3; ++m)
#pragma unroll
        for (int r = 0; r < 4; ++r) {
          int pos = wv*48 + m*16 + lg*4 + r;
          float v = acc2[m][r];
          v = v > 0.f ? v : 0.01f*v;
          h2s[pos*H2STRIDE + ocl] = bf16_rne(v);
        }
    }
    __syncthreads();
    if (tid < 188) {
      int oh = tid >> 1, half = tid & 1;
      int o0  = pass ? (112 + half*44) : (half*56);
      int cnt = pass ? 44 : 56;
      int ol0 = o0 - ocb;
#pragma unroll 1
      for (int tap = 0; tap < 6; ++tap) {
        int kh = tap >> 1, kw = tap & 1;
        int pos = (oh + kh)*2 + kw;
        const uint_t* row = (const uint_t*)(h2s + pos*H2STRIDE + ol0);
        for (int i = 0; i < cnt/2; ++i) {
          uint_t u = row[i];
          float v0 = __uint_as_float(u << 16);
          float v1 = __uint_as_float(u & 0xffff0000u);
          int oc = o0 + i*2;
          s3 += v0 * sm_we3[oc*6 + tap] + v1 * sm_we3[(oc+1)*6 + tap];
        }
      }
    }
  }
  if (tid < 188) s3buf[tid] = s3;
  __syncthreads();
  if (tid < 94) x0b[n*192 + tid] = bf16_rne(tanhf(s3buf[2*tid] + s3buf[2*tid + 1] + be3[0]));
}

// ---------------------------------------------------------------------------
// bf16 MFMA GEMM, N-tiled grid; hi/lo split for dependency distance.
// ---------------------------------------------------------------------------
#define ACT_RELU  1
#define ACT_TANH  2
#define ACT_TANH2 3
#define ACT_LTANH 5
#define ACT_LSIG  6

template<int ACT>
__device__ __forceinline__ float act_apply(float v) {
  if (ACT == ACT_RELU)       v = v > 0.f ? v : 0.f;
  else if (ACT == ACT_TANH)  v = tanhf(v);
  else if (ACT == ACT_TANH2) v = tanhf(tanhf(v));
  else if (ACT == ACT_LTANH) { v = v > 0.f ? v : 0.01f*v; v = tanhf(v); }
  else if (ACT == ACT_LSIG)  { v = v > 0.f ? v : 0.01f*v; v = 1.f/(1.f + expf(-v)); }
  return v;
}

template<int ACT, bool WF32, bool WB16, int NT>
__global__ __launch_bounds__(64) void gemm_bf16_kernel(
    const ushort_t* __restrict__ A, int ldA, int Kp,
    const ushort_t* __restrict__ Bp, int NTtotal,
    const float* __restrict__ bias, int Nreal,
    float* __restrict__ Cf, int ldCf,
    ushort_t* __restrict__ Cb, int ldCb)
{
  const int l  = threadIdx.x;
  const int lg = l >> 4, lc = l & 15;
  const int row0 = blockIdx.x * 32;
  const int nt0  = blockIdx.y * NT;
  f32x4 acc[2][NT];
#pragma unroll
  for (int m = 0; m < 2; ++m)
#pragma unroll
    for (int nt = 0; nt < NT; ++nt) acc[m][nt] = (f32x4){0.f, 0.f, 0.f, 0.f};

  const int steps = Kp >> 5;
#pragma unroll 1
  for (int s = 0; s < steps; ++s) {
    int k0 = s*32 + lg*8;
    bf16x8 a0 = *(const bf16x8*)(A + (size_t)(row0 + lc)*ldA + k0);
    bf16x8 a1 = *(const bf16x8*)(A + (size_t)(row0 + 16 + lc)*ldA + k0);
    const ushort_t* bp = Bp + ((size_t)s*NTtotal + nt0)*1024 + l*8;
#pragma unroll
    for (int nt = 0; nt < NT; ++nt) {
      bf16x8 bh = *(const bf16x8*)(bp + nt*1024);
      acc[0][nt] = __builtin_amdgcn_mfma_f32_16x16x32_bf16(a0, bh, acc[0][nt], 0, 0, 0);
      acc[1][nt] = __builtin_amdgcn_mfma_f32_16x16x32_bf16(a1, bh, acc[1][nt], 0, 0, 0);
    }
#pragma unroll
    for (int nt = 0; nt < NT; ++nt) {
      bf16x8 bl = *(const bf16x8*)(bp + nt*1024 + 512);
      acc[0][nt] = __builtin_amdgcn_mfma_f32_16x16x32_bf16(a0, bl, acc[0][nt], 0, 0, 0);
      acc[1][nt] = __builtin_amdgcn_mfma_f32_16x16x32_bf16(a1, bl, acc[1][nt], 0, 0, 0);
    }
  }

#pragma unroll
  for (int m = 0; m < 2; ++m)
#pragma unroll
    for (int nt = 0; nt < NT; ++nt) {
      int c = (nt0 + nt)*16 + lc;
      if (c < Nreal) {
        float bv = bias[c];
#pragma unroll
        for (int r = 0; r < 4; ++r) {
          int row = row0 + m*16 + lg*4 + r;
          float v = act_apply<ACT>(acc[m][nt][r] + bv);
          if (WF32) Cf[(size_t)row*ldCf + c] = v;
          if (WB16) Cb[(size_t)row*ldCb + c] = bf16_rne(v);
        }
      }
    }
}

// ---------------------------------------------------------------------------
// Graph: CSR build + aggregation (unroll-4 MLP) + segment max (validated r8)
// ---------------------------------------------------------------------------
__global__ void deg_kernel(const int* __restrict__ dst, int* __restrict__ deg) {
  int e = blockIdx.x*256 + threadIdx.x;
  if (e < NE) atomicAdd(&deg[dst[e]], 1);
}

__global__ __launch_bounds__(256) void scan_kernel(
    const int* __restrict__ deg, int* __restrict__ rowptr,
    int* __restrict__ cursor, float* __restrict__ normv)
{
  __shared__ int part[256];
  int t = threadIdx.x;
  int loc[8]; int s = 0;
#pragma unroll
  for (int j = 0; j < 8; ++j) { loc[j] = deg[t*8 + j]; s += loc[j]; }
  part[t] = s; __syncthreads();
  int v = s;
  for (int off = 1; off < 256; off <<= 1) {
    int add = (t >= off) ? part[t - off] : 0;
    __syncthreads();
    v += add; part[t] = v;
    __syncthreads();
  }
  int base = v - s;
#pragma unroll
  for (int j = 0; j < 8; ++j) {
    int idx = t*8 + j;
    rowptr[idx] = base; cursor[idx] = base;
    int d = loc[j];
    normv[idx] = rsqrtf((float)(d < 1 ? 1 : d));
    base += d;
  }
  if (t == 255) rowptr[NN] = base;
}

__global__ void scatter_kernel(const int* __restrict__ src, const int* __restrict__ dst,
                               int* __restrict__ cursor, int* __restrict__ csr) {
  int e = blockIdx.x*256 + threadIdx.x;
  if (e < NE) {
    int p = atomicAdd(&cursor[dst[e]], 1);
    csr[p] = src[e];
  }
}

__global__ void agg_kernel(const float* __restrict__ x, const float* __restrict__ z,
                           float* __restrict__ outf, ushort_t* __restrict__ outb,
                           const int* __restrict__ rowptr, const int* __restrict__ csr,
                           const float* __restrict__ normv, float s1, float s2)
{
  int d = blockIdx.x, c = threadIdx.x;
  int beg = rowptr[d], end = rowptr[d+1];
  float a0 = 0.f, a1 = 0.f, a2 = 0.f, a3 = 0.f;
  int i = beg;
  for (; i + 4 <= end; i += 4) {
    int t0 = csr[i], t1 = csr[i+1], t2 = csr[i+2], t3 = csr[i+3];
    a0 += x[(size_t)t0*512 + c] * normv[t0];
    a1 += x[(size_t)t1*512 + c] * normv[t1];
    a2 += x[(size_t)t2*512 + c] * normv[t2];
    a3 += x[(size_t)t3*512 + c] * normv[t3];
  }
  for (; i < end; ++i) { int t = csr[i]; a0 += x[(size_t)t*512 + c] * normv[t]; }
  float v = s1 * normv[d] * ((a0 + a1) + (a2 + a3));
  if (s2 != 0.f) v += s2 * z[(size_t)d*512 + c];
  outf[(size_t)d*512 + c] = v;
  outb[(size_t)d*512 + c] = bf16_rne(v);
}

__global__ void smax_kernel(const ushort_t* __restrict__ m, int ldm,
                            ushort_t* __restrict__ hn, int ldo,
                            const int* __restrict__ rowptr, const int* __restrict__ csr, int C)
{
  int d = blockIdx.x, c = threadIdx.x;
  if (c >= C) return;
  int beg = rowptr[d], end = rowptr[d+1];
  float a0 = 0.f, a1 = 0.f, a2 = 0.f, a3 = 0.f;
  int i = beg;
  for (; i + 4 <= end; i += 4) {
    int t0 = csr[i], t1 = csr[i+1], t2 = csr[i+2], t3 = csr[i+3];
    a0 = fmaxf(a0, bf16_f(m[(size_t)t0*ldm + c]));
    a1 = fmaxf(a1, bf16_f(m[(size_t)t1*ldm + c]));
    a2 = fmaxf(a2, bf16_f(m[(size_t)t2*ldm + c]));
    a3 = fmaxf(a3, bf16_f(m[(size_t)t3*ldm + c]));
  }
  for (; i < end; ++i) a0 = fmaxf(a0, bf16_f(m[(size_t)csr[i]*ldm + c]));
  hn[(size_t)d*ldo + c] = bf16_rne(fmaxf(fmaxf(a0, a1), fmaxf(a2, a3)));
}

// ---------------------------------------------------------------------------
extern "C" void kernel_launch(void* const* d_in, const int* in_sizes, int n_in,
                              void* d_out, int out_size, void* d_ws, size_t ws_size,
                              hipStream_t stream)
{
  const float* inputs = (const float*)d_in[0];
  const int*   src    = (const int*)d_in[1];
  const int*   dstv   = (const int*)d_in[2];
  const float* We1 = (const float*)d_in[3];
  const float* be1 = (const float*)d_in[4];
  const float* We2 = (const float*)d_in[5];
  const float* be2 = (const float*)d_in[6];
  const float* We3 = (const float*)d_in[7];
  const float* be3 = (const float*)d_in[8];
  const float* Wp1 = (const float*)d_in[9];
  const float* bp1 = (const float*)d_in[10];
  const float* Ws1 = (const float*)d_in[11];
  const float* Wn1 = (const float*)d_in[12];
  const float* b1  = (const float*)d_in[13];
  const float* Wc2 = (const float*)d_in[14];
  const float* bc2 = (const float*)d_in[15];
  const float* Wt3 = (const float*)d_in[16];
  const float* bt3 = (const float*)d_in[17];
  const float* Wp4 = (const float*)d_in[18];
  const float* bp4 = (const float*)d_in[19];
  const float* Ws4 = (const float*)d_in[20];
  const float* Wn4 = (const float*)d_in[21];
  const float* b4  = (const float*)d_in[22];
  const float* Wc5 = (const float*)d_in[23];
  const float* bc5 = (const float*)d_in[24];
  const float* Wt6 = (const float*)d_in[25];
  const float* bt6 = (const float*)d_in[26];
  float* out = (float*)d_out;

  char* w = (char*)d_ws;
  auto alloc = [&](size_t bytes) { char* p = w; w += (bytes + 255) & ~(size_t)255; return p; };
  int*      deg    = (int*)     alloc((size_t)NN*sizeof(int));
  int*      rowptr = (int*)     alloc((size_t)(NN+1)*sizeof(int));
  int*      cursor = (int*)     alloc((size_t)NN*sizeof(int));
  int*      csr    = (int*)     alloc((size_t)NE*sizeof(int));
  float*    normv  = (float*)   alloc((size_t)NN*sizeof(float));
  ushort_t* Wb     = (ushort_t*)alloc((size_t)24*13*1024*sizeof(ushort_t));
  ushort_t* Wg     = (ushort_t*)alloc((size_t)562*1024*sizeof(ushort_t));
  ushort_t* XH1    = (ushort_t*)alloc((size_t)NN*192*sizeof(ushort_t));
  ushort_t* Pb     = (ushort_t*)alloc((size_t)NN*96*sizeof(ushort_t));
  ushort_t* XH4    = (ushort_t*)alloc((size_t)NN*256*sizeof(ushort_t));
  ushort_t* Pb4    = (ushort_t*)alloc((size_t)NN*128*sizeof(ushort_t));
  float*    G1     = (float*)   alloc((size_t)NN*512*sizeof(float));
  float*    G2     = (float*)   alloc((size_t)NN*512*sizeof(float));
  ushort_t* G1b    = (ushort_t*)alloc((size_t)NN*512*sizeof(ushort_t));
  ushort_t* G2b    = (ushort_t*)alloc((size_t)NN*512*sizeof(ushort_t));

  // ---- CSR + norms ----
  hipMemsetAsync(deg, 0, NN*sizeof(int), stream);
  deg_kernel<<<NE/256, 256, 0, stream>>>(dstv, deg);
  scan_kernel<<<1, 256, 0, stream>>>(deg, rowptr, cursor, normv);
  scatter_kernel<<<NE/256, 256, 0, stream>>>(src, dstv, cursor, csr);

  // ---- weight preps ----
  wprep_kernel<<<(24*13*64*8 + 255)/256, 256, 0, stream>>>(We2, Wb);
  WPack p;
  p.d[0] = {Wp1, Wp1,  94,  94,  94, 6,   0};   // pool1  Kp=96
  p.d[1] = {Ws1, Wn1,  94, 188, 128, 8,  18};   // main1  Kp=192
  p.d[2] = {Wc2, Wc2, 512, 512, 128, 8,  66};   // cheb2  Kp=512
  p.d[3] = {Wt3, Wt3, 512, 512, 128, 8, 194};   // tag3   Kp=512
  p.d[4] = {Wp4, Wp4, 128, 128, 128, 8, 322};   // pool4  Kp=128
  p.d[5] = {Ws4, Wn4, 128, 256, 128, 8, 354};   // main4  Kp=256
  p.d[6] = {Wc5, Wc5, 512, 512, 128, 8, 418};   // cheb5  Kp=512
  p.d[7] = {Wt6, Wt6, 512, 512,  16, 1, 546};   // tag6   Kp=512 -> total 562
  wprep_gemm_kernel<<<562, 256, 0, stream>>>(p, Wg);

  // ---- encoder -> XH1 cols 0-93 (bf16) ----
  encoder_kernel<<<NN, 256, 0, stream>>>(inputs, We1, be1, Wb, be2, We3, be3, XH1);

  const int GM = NN/32;   // 64 row-blocks
  // ---- sage1: pool GEMM -> smax -> concat GEMM ----
  gemm_bf16_kernel<ACT_RELU, false, true, 2><<<dim3(GM,3), 64, 0, stream>>>(
      XH1, 192, 96, Wg + (size_t)0*1024, 6, bp1, 94, nullptr, 0, Pb, 96);
  smax_kernel<<<NN, 128, 0, stream>>>(Pb, 96, XH1 + 94, 192, rowptr, csr, 94);
  gemm_bf16_kernel<ACT_TANH2, true, true, 2><<<dim3(GM,4), 64, 0, stream>>>(
      XH1, 192, 192, Wg + (size_t)18*1024, 8, b1, 128, G1, 512, G1b, 512);
  // ---- cheb2 ----
  agg_kernel<<<NN, 128, 0, stream>>>(G1,       G1,       G1 + 128, G1b + 128, rowptr, csr, normv, -1.f,  0.f);
  agg_kernel<<<NN, 128, 0, stream>>>(G1 + 128, G1,       G1 + 256, G1b + 256, rowptr, csr, normv, -2.f, -1.f);
  agg_kernel<<<NN, 128, 0, stream>>>(G1 + 256, G1 + 128, G1 + 384, G1b + 384, rowptr, csr, normv, -2.f, -1.f);
  gemm_bf16_kernel<ACT_TANH, true, true, 2><<<dim3(GM,4), 64, 0, stream>>>(
      G1b, 512, 512, Wg + (size_t)66*1024, 8, bc2, 128, G2, 512, G2b, 512);
  // ---- tag3 ----
  agg_kernel<<<NN, 128, 0, stream>>>(G2,       G2, G2 + 128, G2b + 128, rowptr, csr, normv, 1.f, 0.f);
  agg_kernel<<<NN, 128, 0, stream>>>(G2 + 128, G2, G2 + 256, G2b + 256, rowptr, csr, normv, 1.f, 0.f);
  agg_kernel<<<NN, 128, 0, stream>>>(G2 + 256, G2, G2 + 384, G2b + 384, rowptr, csr, normv, 1.f, 0.f);
  gemm_bf16_kernel<ACT_LTANH, false, true, 2><<<dim3(GM,4), 64, 0, stream>>>(
      G2b, 512, 512, Wg + (size_t)194*1024, 8, bt3, 128, nullptr, 0, XH4, 256);
  // ---- sage4 ----
  gemm_bf16_kernel<ACT_RELU, false, true, 2><<<dim3(GM,4), 64, 0, stream>>>(
      XH4, 256, 128, Wg + (size_t)322*1024, 8, bp4, 128, nullptr, 0, Pb4, 128);
  smax_kernel<<<NN, 128, 0, stream>>>(Pb4, 128, XH4 + 128, 256, rowptr, csr, 128);
  gemm_bf16_kernel<ACT_TANH2, true, true, 2><<<dim3(GM,4), 64, 0, stream>>>(
      XH4, 256, 256, Wg + (size_t)354*1024, 8, b4, 128, G1, 512, G1b, 512);
  // ---- cheb5 ----
  agg_kernel<<<NN, 128, 0, stream>>>(G1,       G1,       G1 + 128, G1b + 128, rowptr, csr, normv, -1.f,  0.f);
  agg_kernel<<<NN, 128, 0, stream>>>(G1 + 128, G1,       G1 + 256, G1b + 256, rowptr, csr, normv, -2.f, -1.f);
  agg_kernel<<<NN, 128, 0, stream>>>(G1 + 256, G1 + 128, G1 + 384, G1b + 384, rowptr, csr, normv, -2.f, -1.f);
  gemm_bf16_kernel<ACT_TANH, true, true, 2><<<dim3(GM,4), 64, 0, stream>>>(
      G1b, 512, 512, Wg + (size_t)418*1024, 8, bc5, 128, G2, 512, G2b, 512);
  // ---- tag6 ----
  agg_kernel<<<NN, 128, 0, stream>>>(G2,       G2, G2 + 128, G2b + 128, rowptr, csr, normv, 1.f, 0.f);
  agg_kernel<<<NN, 128, 0, stream>>>(G2 + 128, G2, G2 + 256, G2b + 256, rowptr, csr, normv, 1.f, 0.f);
  agg_kernel<<<NN, 128, 0, stream>>>(G2 + 256, G2, G2 + 384, G2b + 384, rowptr, csr, normv, 1.f, 0.f);
  gemm_bf16_kernel<ACT_LSIG, true, false, 1><<<dim3(GM,1), 64, 0, stream>>>(
      G2b, 512, 512, Wg + (size_t)546*1024, 1, bt6, 16, out, 16, nullptr, 0);
}

// Round 11
// 578.210 us; speedup vs baseline: 1.0554x; 1.0554x over previous
//
#include <hip/hip_runtime.h>
#include <math.h>

#define NN 2048
#define NE 65536
#define HID 128

typedef unsigned int uint_t;
typedef unsigned short ushort_t;
typedef __attribute__((ext_vector_type(8))) short bf16x8;
typedef __attribute__((ext_vector_type(4))) float f32x4;

__device__ __forceinline__ ushort_t bf16_rne(float f) {
  uint_t u = __float_as_uint(f);
  return (ushort_t)((u + 0x7fffu + ((u >> 16) & 1u)) >> 16);
}
__device__ __forceinline__ float bf16_f(ushort_t h) {
  return __uint_as_float(((uint_t)h) << 16);
}

// ---------------------------------------------------------------------------
// Encoder weight prep (validated r5): We2 -> MFMA B-frags, bf16 hi/lo.
// ---------------------------------------------------------------------------
__global__ void wprep_kernel(const float* __restrict__ We2, ushort_t* __restrict__ Wb) {
  int idx = blockIdx.x*256 + threadIdx.x;          // over (s,nt,l,j) = 24*13*64*8
  if (idx >= 24*13*64*8) return;
  int j = idx & 7;
  int l = (idx >> 3) & 63;
  int t = idx >> 9;                                // s*13 + nt
  int s = t / 13, nt = t - s*13;
  int oc = nt*16 + (l & 15);
  int ic = (s & 3)*32 + (l >> 4)*8 + j;
  int tap = s >> 2, kh = tap >> 1, kw = tap & 1;
  float wv = (oc < 200 && ic < 100) ? We2[((oc*100 + ic)*3 + kh)*2 + kw] : 0.f;
  ushort_t hi = bf16_rne(wv);
  float lo = wv - bf16_f(hi);
  Wb[t*1024 + l*8 + j]       = hi;
  Wb[t*1024 + 512 + l*8 + j] = bf16_rne(lo);
}

// ---------------------------------------------------------------------------
// Generic GEMM weight prep (validated r7)
// ---------------------------------------------------------------------------
struct WDesc {
  const float* s0; const float* s1;
  int K0; int K; int N; int NT; int tileStart;
};
struct WPack { WDesc d[8]; };

__global__ __launch_bounds__(256) void wprep_gemm_kernel(WPack p, ushort_t* __restrict__ Wg) {
  int b = blockIdx.x;
  int g = 0;
  while (g < 7 && b >= p.d[g+1].tileStart) ++g;
  const WDesc& d = p.d[g];
  int t = b - d.tileStart;
  int s = t / d.NT, nt = t - s*d.NT;
  size_t base = (size_t)b * 1024;
#pragma unroll
  for (int u = 0; u < 2; ++u) {
    int pos = threadIdx.x*2 + u;          // 0..511
    int l = pos >> 3, j = pos & 7;
    int k = s*32 + (l >> 4)*8 + j;
    int n = nt*16 + (l & 15);
    float wv = 0.f;
    if (k < d.K && n < d.N)
      wv = (k < d.K0) ? d.s0[k*d.N + n] : d.s1[(k - d.K0)*d.N + n];
    ushort_t hi = bf16_rne(wv);
    float lo = wv - bf16_f(hi);
    Wg[base + pos]       = hi;
    Wg[base + 512 + pos] = bf16_rne(lo);
  }
}

// ---------------------------------------------------------------------------
// Fused encoder v6: v4 structure + M-PAIR hi/lo issue (dep distance 6, only
// a0/a1 extra live — r9 register footprint, no spill). Per-acc order hi->lo
// unchanged -> bit-exact vs r9/r10.
// ---------------------------------------------------------------------------
#define H1_USHORTS (294*104 + 64)
#define H2STRIDE 114

__global__ __launch_bounds__(256, 2) void encoder_kernel(
    const float* __restrict__ inputs,
    const float* __restrict__ We1, const float* __restrict__ be1,
    const ushort_t* __restrict__ Wb, const float* __restrict__ be2,
    const float* __restrict__ We3, const float* __restrict__ be3,
    ushort_t* __restrict__ x0b)
{
  __shared__ __align__(16) ushort_t h1[H1_USHORTS];
  __shared__ float sm_x[500];
  __shared__ float sm_w1[900];
  __shared__ float sm_b1[100];
  __shared__ float sm_we3[1200];
  __shared__ float s3buf[188];

  const int n   = blockIdx.x;
  const int tid = threadIdx.x;
  const int l   = tid & 63;
  const int wv  = tid >> 6;
  const int lg  = l >> 4;
  const int lc  = l & 15;
  const int ntb = wv*3;          // this wave's N-tile base (tiles ntb..ntb+2)

  // ---- zero h1 + stage params ----
  {
    uint_t* h1u = (uint_t*)h1;
    for (int i = tid; i < H1_USHORTS/2; i += 256) h1u[i] = 0u;
  }
  for (int i = tid; i < 500;  i += 256) sm_x[i]   = inputs[n*500 + i];
  for (int i = tid; i < 900;  i += 256) sm_w1[i]  = We1[i];
  for (int i = tid; i < 1200; i += 256) sm_we3[i] = We3[i];
  if (tid < 100) sm_b1[tid] = be1[tid];
  __syncthreads();

  // ---- conv1 -> leaky -> h1 bf16 [294 rows][104 stride] ----
  for (int i = tid; i < 29400; i += 256) {
    int p = i / 100, oc = i - p*100;
    int h = p / 3,  w  = p - h*3;
    float a = sm_b1[oc];
#pragma unroll
    for (int kh = 0; kh < 3; ++kh)
#pragma unroll
      for (int kw = 0; kw < 3; ++kw)
        a += sm_x[(h + kh)*5 + (w + kw)] * sm_w1[oc*9 + kh*3 + kw];
    a = a > 0.f ? a : 0.01f*a;
    h1[p*104 + oc] = bf16_rne(a);
  }
  __syncthreads();

  // ---- main conv2 GEMM: wave owns N-tiles ntb..ntb+2, ALL 12 M-tiles ----
  int rowb[12];
#pragma unroll
  for (int m = 0; m < 12; ++m) {
    int pos = m*16 + lc;
    rowb[m] = ((pos >> 1)*3 + (pos & 1))*104;
  }
  f32x4 acc[12][3];
#pragma unroll
  for (int nt = 0; nt < 3; ++nt) {
    float b = be2[(ntb + nt)*16 + lc];     // tiles 0..11 -> oc < 192, always real
#pragma unroll
    for (int m = 0; m < 12; ++m) acc[m][nt] = (f32x4){b, b, b, b};
  }

  bf16x8 Bh0[3], Bl0[3], Bh1[3], Bl1[3];
  auto LOADB = [&](bf16x8 (&bh)[3], bf16x8 (&bl)[3], int s) {
    const ushort_t* bp = Wb + (size_t)(s*13 + ntb)*1024 + l*8;
#pragma unroll
    for (int nt = 0; nt < 3; ++nt) {
      bh[nt] = *(const bf16x8*)(bp + nt*1024);
      bl[nt] = *(const bf16x8*)(bp + nt*1024 + 512);
    }
  };
  // M-pair issue: per pair, 6 independent hi-MFMAs then 6 lo-MFMAs.
  // Per-acc order hi->lo preserved (bit-exact); dep distance 1 -> 6.
  auto COMP = [&](bf16x8 (&bh)[3], bf16x8 (&bl)[3], int s) {
    int tap = s >> 2;
    int uofs = ((tap >> 1)*3 + (tap & 1))*104 + (s & 3)*32 + lg*8;
#pragma unroll
    for (int m = 0; m < 12; m += 2) {
      bf16x8 a0 = *(const bf16x8*)(h1 + rowb[m] + uofs);
      bf16x8 a1 = *(const bf16x8*)(h1 + rowb[m + 1] + uofs);
#pragma unroll
      for (int nt = 0; nt < 3; ++nt)
        acc[m][nt] = __builtin_amdgcn_mfma_f32_16x16x32_bf16(a0, bh[nt], acc[m][nt], 0, 0, 0);
#pragma unroll
      for (int nt = 0; nt < 3; ++nt)
        acc[m+1][nt] = __builtin_amdgcn_mfma_f32_16x16x32_bf16(a1, bh[nt], acc[m+1][nt], 0, 0, 0);
#pragma unroll
      for (int nt = 0; nt < 3; ++nt)
        acc[m][nt] = __builtin_amdgcn_mfma_f32_16x16x32_bf16(a0, bl[nt], acc[m][nt], 0, 0, 0);
#pragma unroll
      for (int nt = 0; nt < 3; ++nt)
        acc[m+1][nt] = __builtin_amdgcn_mfma_f32_16x16x32_bf16(a1, bl[nt], acc[m+1][nt], 0, 0, 0);
    }
  };

  LOADB(Bh0, Bl0, 0);
#pragma unroll 1
  for (int s = 0; s < 24; s += 2) {
    LOADB(Bh1, Bl1, s + 1);
    COMP(Bh0, Bl0, s);
    if (s + 2 < 24) LOADB(Bh0, Bl0, s + 2);
    COMP(Bh1, Bl1, s + 1);
  }

  // ---- tail tile 12 (oc 192..207): M-split by wave, rows wv*48..+47 ----
  int rowb2[3];
#pragma unroll
  for (int m = 0; m < 3; ++m) {
    int pos = wv*48 + m*16 + lc;
    rowb2[m] = ((pos >> 1)*3 + (pos & 1))*104;
  }
  f32x4 acc2[3];
  {
    int oc = 192 + lc;
    float b = (oc < 200) ? be2[oc] : 0.f;
#pragma unroll
    for (int m = 0; m < 3; ++m) acc2[m] = (f32x4){b, b, b, b};
  }
  bf16x8 th0, tl0, th1, tl1;
  auto LOADT = [&](bf16x8& th, bf16x8& tl, int s) {
    const ushort_t* bp = Wb + (size_t)(s*13 + 12)*1024 + l*8;
    th = *(const bf16x8*)(bp);
    tl = *(const bf16x8*)(bp + 512);
  };
  auto COMPT = [&](bf16x8& th, bf16x8& tl, int s) {
    int tap = s >> 2;
    int uofs = ((tap >> 1)*3 + (tap & 1))*104 + (s & 3)*32 + lg*8;
    bf16x8 a0 = *(const bf16x8*)(h1 + rowb2[0] + uofs);
    bf16x8 a1 = *(const bf16x8*)(h1 + rowb2[1] + uofs);
    bf16x8 a2 = *(const bf16x8*)(h1 + rowb2[2] + uofs);
    acc2[0] = __builtin_amdgcn_mfma_f32_16x16x32_bf16(a0, th, acc2[0], 0, 0, 0);
    acc2[1] = __builtin_amdgcn_mfma_f32_16x16x32_bf16(a1, th, acc2[1], 0, 0, 0);
    acc2[2] = __builtin_amdgcn_mfma_f32_16x16x32_bf16(a2, th, acc2[2], 0, 0, 0);
    acc2[0] = __builtin_amdgcn_mfma_f32_16x16x32_bf16(a0, tl, acc2[0], 0, 0, 0);
    acc2[1] = __builtin_amdgcn_mfma_f32_16x16x32_bf16(a1, tl, acc2[1], 0, 0, 0);
    acc2[2] = __builtin_amdgcn_mfma_f32_16x16x32_bf16(a2, tl, acc2[2], 0, 0, 0);
  };
  LOADT(th0, tl0, 0);
#pragma unroll 1
  for (int s = 0; s < 24; s += 2) {
    LOADT(th1, tl1, s + 1);
    COMPT(th0, tl0, s);
    if (s + 2 < 24) LOADT(th0, tl0, s + 2);
    COMPT(th1, tl1, s + 1);
  }

  // ---- leaky(h2) -> LDS (reuse h1) in two oc-halves, conv3 partials ----
  ushort_t* h2s = h1;
  float s3 = 0.f;
#pragma unroll 1
  for (int pass = 0; pass < 2; ++pass) {
    const int ocb = pass ? 112 : 0;
    __syncthreads();   // pass0: all h1 GEMM reads done; pass1: conv3 pass0 reads done
#pragma unroll
    for (int nt = 0; nt < 3; ++nt) {
      int t = ntb + nt;
      bool inc = pass ? (t >= 7) : (t < 7);
      if (inc) {
        int ocl = t*16 + lc - ocb;
#pragma unroll
        for (int m = 0; m < 12; ++m)
#pragma unroll
          for (int r = 0; r < 4; ++r) {
            int pos = m*16 + lg*4 + r;
            float v = acc[m][nt][r];
            v = v > 0.f ? v : 0.01f*v;
            h2s[pos*H2STRIDE + ocl] = bf16_rne(v);
          }
      }
    }
    if (pass == 1) {
      int ocl = 80 + lc;   // oc = 192+lc, minus ocb=112
#pragma unroll
      for (int m = 0; m < 3; ++m)
#pragma unroll
        for (int r = 0; r < 4; ++r) {
          int pos = wv*48 + m*16 + lg*4 + r;
          float v = acc2[m][r];
          v = v > 0.f ? v : 0.01f*v;
          h2s[pos*H2STRIDE + ocl] = bf16_rne(v);
        }
    }
    __syncthreads();
    if (tid < 188) {
      int oh = tid >> 1, half = tid & 1;
      int o0  = pass ? (112 + half*44) : (half*56);
      int cnt = pass ? 44 : 56;
      int ol0 = o0 - ocb;
#pragma unroll 1
      for (int tap = 0; tap < 6; ++tap) {
        int kh = tap >> 1, kw = tap & 1;
        int pos = (oh + kh)*2 + kw;
        const uint_t* row = (const uint_t*)(h2s + pos*H2STRIDE + ol0);
        for (int i = 0; i < cnt/2; ++i) {
          uint_t u = row[i];
          float v0 = __uint_as_float(u << 16);
          float v1 = __uint_as_float(u & 0xffff0000u);
          int oc = o0 + i*2;
          s3 += v0 * sm_we3[oc*6 + tap] + v1 * sm_we3[(oc+1)*6 + tap];
        }
      }
    }
  }
  if (tid < 188) s3buf[tid] = s3;
  __syncthreads();
  if (tid < 94) x0b[n*192 + tid] = bf16_rne(tanhf(s3buf[2*tid] + s3buf[2*tid + 1] + be3[0]));
}

// ---------------------------------------------------------------------------
// bf16 MFMA GEMM, N-tiled grid; hi/lo split for dependency distance.
// ---------------------------------------------------------------------------
#define ACT_RELU  1
#define ACT_TANH  2
#define ACT_TANH2 3
#define ACT_LTANH 5
#define ACT_LSIG  6

template<int ACT>
__device__ __forceinline__ float act_apply(float v) {
  if (ACT == ACT_RELU)       v = v > 0.f ? v : 0.f;
  else if (ACT == ACT_TANH)  v = tanhf(v);
  else if (ACT == ACT_TANH2) v = tanhf(tanhf(v));
  else if (ACT == ACT_LTANH) { v = v > 0.f ? v : 0.01f*v; v = tanhf(v); }
  else if (ACT == ACT_LSIG)  { v = v > 0.f ? v : 0.01f*v; v = 1.f/(1.f + expf(-v)); }
  return v;
}

template<int ACT, bool WF32, bool WB16, int NT>
__global__ __launch_bounds__(64) void gemm_bf16_kernel(
    const ushort_t* __restrict__ A, int ldA, int Kp,
    const ushort_t* __restrict__ Bp, int NTtotal,
    const float* __restrict__ bias, int Nreal,
    float* __restrict__ Cf, int ldCf,
    ushort_t* __restrict__ Cb, int ldCb)
{
  const int l  = threadIdx.x;
  const int lg = l >> 4, lc = l & 15;
  const int row0 = blockIdx.x * 32;
  const int nt0  = blockIdx.y * NT;
  f32x4 acc[2][NT];
#pragma unroll
  for (int m = 0; m < 2; ++m)
#pragma unroll
    for (int nt = 0; nt < NT; ++nt) acc[m][nt] = (f32x4){0.f, 0.f, 0.f, 0.f};

  const int steps = Kp >> 5;
#pragma unroll 1
  for (int s = 0; s < steps; ++s) {
    int k0 = s*32 + lg*8;
    bf16x8 a0 = *(const bf16x8*)(A + (size_t)(row0 + lc)*ldA + k0);
    bf16x8 a1 = *(const bf16x8*)(A + (size_t)(row0 + 16 + lc)*ldA + k0);
    const ushort_t* bp = Bp + ((size_t)s*NTtotal + nt0)*1024 + l*8;
#pragma unroll
    for (int nt = 0; nt < NT; ++nt) {
      bf16x8 bh = *(const bf16x8*)(bp + nt*1024);
      acc[0][nt] = __builtin_amdgcn_mfma_f32_16x16x32_bf16(a0, bh, acc[0][nt], 0, 0, 0);
      acc[1][nt] = __builtin_amdgcn_mfma_f32_16x16x32_bf16(a1, bh, acc[1][nt], 0, 0, 0);
    }
#pragma unroll
    for (int nt = 0; nt < NT; ++nt) {
      bf16x8 bl = *(const bf16x8*)(bp + nt*1024 + 512);
      acc[0][nt] = __builtin_amdgcn_mfma_f32_16x16x32_bf16(a0, bl, acc[0][nt], 0, 0, 0);
      acc[1][nt] = __builtin_amdgcn_mfma_f32_16x16x32_bf16(a1, bl, acc[1][nt], 0, 0, 0);
    }
  }

#pragma unroll
  for (int m = 0; m < 2; ++m)
#pragma unroll
    for (int nt = 0; nt < NT; ++nt) {
      int c = (nt0 + nt)*16 + lc;
      if (c < Nreal) {
        float bv = bias[c];
#pragma unroll
        for (int r = 0; r < 4; ++r) {
          int row = row0 + m*16 + lg*4 + r;
          float v = act_apply<ACT>(acc[m][nt][r] + bv);
          if (WF32) Cf[(size_t)row*ldCf + c] = v;
          if (WB16) Cb[(size_t)row*ldCb + c] = bf16_rne(v);
        }
      }
    }
}

// ---------------------------------------------------------------------------
// Graph: CSR build + aggregation (unroll-4 MLP) + segment max (validated r8)
// ---------------------------------------------------------------------------
__global__ void deg_kernel(const int* __restrict__ dst, int* __restrict__ deg) {
  int e = blockIdx.x*256 + threadIdx.x;
  if (e < NE) atomicAdd(&deg[dst[e]], 1);
}

__global__ __launch_bounds__(256) void scan_kernel(
    const int* __restrict__ deg, int* __restrict__ rowptr,
    int* __restrict__ cursor, float* __restrict__ normv)
{
  __shared__ int part[256];
  int t = threadIdx.x;
  int loc[8]; int s = 0;
#pragma unroll
  for (int j = 0; j < 8; ++j) { loc[j] = deg[t*8 + j]; s += loc[j]; }
  part[t] = s; __syncthreads();
  int v = s;
  for (int off = 1; off < 256; off <<= 1) {
    int add = (t >= off) ? part[t - off] : 0;
    __syncthreads();
    v += add; part[t] = v;
    __syncthreads();
  }
  int base = v - s;
#pragma unroll
  for (int j = 0; j < 8; ++j) {
    int idx = t*8 + j;
    rowptr[idx] = base; cursor[idx] = base;
    int d = loc[j];
    normv[idx] = rsqrtf((float)(d < 1 ? 1 : d));
    base += d;
  }
  if (t == 255) rowptr[NN] = base;
}

__global__ void scatter_kernel(const int* __restrict__ src, const int* __restrict__ dst,
                               int* __restrict__ cursor, int* __restrict__ csr) {
  int e = blockIdx.x*256 + threadIdx.x;
  if (e < NE) {
    int p = atomicAdd(&cursor[dst[e]], 1);
    csr[p] = src[e];
  }
}

__global__ void agg_kernel(const float* __restrict__ x, const float* __restrict__ z,
                           float* __restrict__ outf, ushort_t* __restrict__ outb,
                           const int* __restrict__ rowptr, const int* __restrict__ csr,
                           const float* __restrict__ normv, float s1, float s2)
{
  int d = blockIdx.x, c = threadIdx.x;
  int beg = rowptr[d], end = rowptr[d+1];
  float a0 = 0.f, a1 = 0.f, a2 = 0.f, a3 = 0.f;
  int i = beg;
  for (; i + 4 <= end; i += 4) {
    int t0 = csr[i], t1 = csr[i+1], t2 = csr[i+2], t3 = csr[i+3];
    a0 += x[(size_t)t0*512 + c] * normv[t0];
    a1 += x[(size_t)t1*512 + c] * normv[t1];
    a2 += x[(size_t)t2*512 + c] * normv[t2];
    a3 += x[(size_t)t3*512 + c] * normv[t3];
  }
  for (; i < end; ++i) { int t = csr[i]; a0 += x[(size_t)t*512 + c] * normv[t]; }
  float v = s1 * normv[d] * ((a0 + a1) + (a2 + a3));
  if (s2 != 0.f) v += s2 * z[(size_t)d*512 + c];
  outf[(size_t)d*512 + c] = v;
  outb[(size_t)d*512 + c] = bf16_rne(v);
}

__global__ void smax_kernel(const ushort_t* __restrict__ m, int ldm,
                            ushort_t* __restrict__ hn, int ldo,
                            const int* __restrict__ rowptr, const int* __restrict__ csr, int C)
{
  int d = blockIdx.x, c = threadIdx.x;
  if (c >= C) return;
  int beg = rowptr[d], end = rowptr[d+1];
  float a0 = 0.f, a1 = 0.f, a2 = 0.f, a3 = 0.f;
  int i = beg;
  for (; i + 4 <= end; i += 4) {
    int t0 = csr[i], t1 = csr[i+1], t2 = csr[i+2], t3 = csr[i+3];
    a0 = fmaxf(a0, bf16_f(m[(size_t)t0*ldm + c]));
    a1 = fmaxf(a1, bf16_f(m[(size_t)t1*ldm + c]));
    a2 = fmaxf(a2, bf16_f(m[(size_t)t2*ldm + c]));
    a3 = fmaxf(a3, bf16_f(m[(size_t)t3*ldm + c]));
  }
  for (; i < end; ++i) a0 = fmaxf(a0, bf16_f(m[(size_t)csr[i]*ldm + c]));
  hn[(size_t)d*ldo + c] = bf16_rne(fmaxf(fmaxf(a0, a1), fmaxf(a2, a3)));
}

// ---------------------------------------------------------------------------
extern "C" void kernel_launch(void* const* d_in, const int* in_sizes, int n_in,
                              void* d_out, int out_size, void* d_ws, size_t ws_size,
                              hipStream_t stream)
{
  const float* inputs = (const float*)d_in[0];
  const int*   src    = (const int*)d_in[1];
  const int*   dstv   = (const int*)d_in[2];
  const float* We1 = (const float*)d_in[3];
  const float* be1 = (const float*)d_in[4];
  const float* We2 = (const float*)d_in[5];
  const float* be2 = (const float*)d_in[6];
  const float* We3 = (const float*)d_in[7];
  const float* be3 = (const float*)d_in[8];
  const float* Wp1 = (const float*)d_in[9];
  const float* bp1 = (const float*)d_in[10];
  const float* Ws1 = (const float*)d_in[11];
  const float* Wn1 = (const float*)d_in[12];
  const float* b1  = (const float*)d_in[13];
  const float* Wc2 = (const float*)d_in[14];
  const float* bc2 = (const float*)d_in[15];
  const float* Wt3 = (const float*)d_in[16];
  const float* bt3 = (const float*)d_in[17];
  const float* Wp4 = (const float*)d_in[18];
  const float* bp4 = (const float*)d_in[19];
  const float* Ws4 = (const float*)d_in[20];
  const float* Wn4 = (const float*)d_in[21];
  const float* b4  = (const float*)d_in[22];
  const float* Wc5 = (const float*)d_in[23];
  const float* bc5 = (const float*)d_in[24];
  const float* Wt6 = (const float*)d_in[25];
  const float* bt6 = (const float*)d_in[26];
  float* out = (float*)d_out;

  char* w = (char*)d_ws;
  auto alloc = [&](size_t bytes) { char* p = w; w += (bytes + 255) & ~(size_t)255; return p; };
  int*      deg    = (int*)     alloc((size_t)NN*sizeof(int));
  int*      rowptr = (int*)     alloc((size_t)(NN+1)*sizeof(int));
  int*      cursor = (int*)     alloc((size_t)NN*sizeof(int));
  int*      csr    = (int*)     alloc((size_t)NE*sizeof(int));
  float*    normv  = (float*)   alloc((size_t)NN*sizeof(float));
  ushort_t* Wb     = (ushort_t*)alloc((size_t)24*13*1024*sizeof(ushort_t));
  ushort_t* Wg     = (ushort_t*)alloc((size_t)562*1024*sizeof(ushort_t));
  ushort_t* XH1    = (ushort_t*)alloc((size_t)NN*192*sizeof(ushort_t));
  ushort_t* Pb     = (ushort_t*)alloc((size_t)NN*96*sizeof(ushort_t));
  ushort_t* XH4    = (ushort_t*)alloc((size_t)NN*256*sizeof(ushort_t));
  ushort_t* Pb4    = (ushort_t*)alloc((size_t)NN*128*sizeof(ushort_t));
  float*    G1     = (float*)   alloc((size_t)NN*512*sizeof(float));
  float*    G2     = (float*)   alloc((size_t)NN*512*sizeof(float));
  ushort_t* G1b    = (ushort_t*)alloc((size_t)NN*512*sizeof(ushort_t));
  ushort_t* G2b    = (ushort_t*)alloc((size_t)NN*512*sizeof(ushort_t));

  // ---- CSR + norms ----
  hipMemsetAsync(deg, 0, NN*sizeof(int), stream);
  deg_kernel<<<NE/256, 256, 0, stream>>>(dstv, deg);
  scan_kernel<<<1, 256, 0, stream>>>(deg, rowptr, cursor, normv);
  scatter_kernel<<<NE/256, 256, 0, stream>>>(src, dstv, cursor, csr);

  // ---- weight preps ----
  wprep_kernel<<<(24*13*64*8 + 255)/256, 256, 0, stream>>>(We2, Wb);
  WPack p;
  p.d[0] = {Wp1, Wp1,  94,  94,  94, 6,   0};   // pool1  Kp=96
  p.d[1] = {Ws1, Wn1,  94, 188, 128, 8,  18};   // main1  Kp=192
  p.d[2] = {Wc2, Wc2, 512, 512, 128, 8,  66};   // cheb2  Kp=512
  p.d[3] = {Wt3, Wt3, 512, 512, 128, 8, 194};   // tag3   Kp=512
  p.d[4] = {Wp4, Wp4, 128, 128, 128, 8, 322};   // pool4  Kp=128
  p.d[5] = {Ws4, Wn4, 128, 256, 128, 8, 354};   // main4  Kp=256
  p.d[6] = {Wc5, Wc5, 512, 512, 128, 8, 418};   // cheb5  Kp=512
  p.d[7] = {Wt6, Wt6, 512, 512,  16, 1, 546};   // tag6   Kp=512 -> total 562
  wprep_gemm_kernel<<<562, 256, 0, stream>>>(p, Wg);

  // ---- encoder -> XH1 cols 0-93 (bf16) ----
  encoder_kernel<<<NN, 256, 0, stream>>>(inputs, We1, be1, Wb, be2, We3, be3, XH1);

  const int GM = NN/32;   // 64 row-blocks
  // ---- sage1: pool GEMM -> smax -> concat GEMM ----
  gemm_bf16_kernel<ACT_RELU, false, true, 2><<<dim3(GM,3), 64, 0, stream>>>(
      XH1, 192, 96, Wg + (size_t)0*1024, 6, bp1, 94, nullptr, 0, Pb, 96);
  smax_kernel<<<NN, 128, 0, stream>>>(Pb, 96, XH1 + 94, 192, rowptr, csr, 94);
  gemm_bf16_kernel<ACT_TANH2, true, true, 2><<<dim3(GM,4), 64, 0, stream>>>(
      XH1, 192, 192, Wg + (size_t)18*1024, 8, b1, 128, G1, 512, G1b, 512);
  // ---- cheb2 ----
  agg_kernel<<<NN, 128, 0, stream>>>(G1,       G1,       G1 + 128, G1b + 128, rowptr, csr, normv, -1.f,  0.f);
  agg_kernel<<<NN, 128, 0, stream>>>(G1 + 128, G1,       G1 + 256, G1b + 256, rowptr, csr, normv, -2.f, -1.f);
  agg_kernel<<<NN, 128, 0, stream>>>(G1 + 256, G1 + 128, G1 + 384, G1b + 384, rowptr, csr, normv, -2.f, -1.f);
  gemm_bf16_kernel<ACT_TANH, true, true, 2><<<dim3(GM,4), 64, 0, stream>>>(
      G1b, 512, 512, Wg + (size_t)66*1024, 8, bc2, 128, G2, 512, G2b, 512);
  // ---- tag3 ----
  agg_kernel<<<NN, 128, 0, stream>>>(G2,       G2, G2 + 128, G2b + 128, rowptr, csr, normv, 1.f, 0.f);
  agg_kernel<<<NN, 128, 0, stream>>>(G2 + 128, G2, G2 + 256, G2b + 256, rowptr, csr, normv, 1.f, 0.f);
  agg_kernel<<<NN, 128, 0, stream>>>(G2 + 256, G2, G2 + 384, G2b + 384, rowptr, csr, normv, 1.f, 0.f);
  gemm_bf16_kernel<ACT_LTANH, false, true, 2><<<dim3(GM,4), 64, 0, stream>>>(
      G2b, 512, 512, Wg + (size_t)194*1024, 8, bt3, 128, nullptr, 0, XH4, 256);
  // ---- sage4 ----
  gemm_bf16_kernel<ACT_RELU, false, true, 2><<<dim3(GM,4), 64, 0, stream>>>(
      XH4, 256, 128, Wg + (size_t)322*1024, 8, bp4, 128, nullptr, 0, Pb4, 128);
  smax_kernel<<<NN, 128, 0, stream>>>(Pb4, 128, XH4 + 128, 256, rowptr, csr, 128);
  gemm_bf16_kernel<ACT_TANH2, true, true, 2><<<dim3(GM,4), 64, 0, stream>>>(
      XH4, 256, 256, Wg + (size_t)354*1024, 8, b4, 128, G1, 512, G1b, 512);
  // ---- cheb5 ----
  agg_kernel<<<NN, 128, 0, stream>>>(G1,       G1,       G1 + 128, G1b + 128, rowptr, csr, normv, -1.f,  0.f);
  agg_kernel<<<NN, 128, 0, stream>>>(G1 + 128, G1,       G1 + 256, G1b + 256, rowptr, csr, normv, -2.f, -1.f);
  agg_kernel<<<NN, 128, 0, stream>>>(G1 + 256, G1 + 128, G1 + 384, G1b + 384, rowptr, csr, normv, -2.f, -1.f);
  gemm_bf16_kernel<ACT_TANH, true, true, 2><<<dim3(GM,4), 64, 0, stream>>>(
      G1b, 512, 512, Wg + (size_t)418*1024, 8, bc5, 128, G2, 512, G2b, 512);
  // ---- tag6 ----
  agg_kernel<<<NN, 128, 0, stream>>>(G2,       G2, G2 + 128, G2b + 128, rowptr, csr, normv, 1.f, 0.f);
  agg_kernel<<<NN, 128, 0, stream>>>(G2 + 128, G2, G2 + 256, G2b + 256, rowptr, csr, normv, 1.f, 0.f);
  agg_kernel<<<NN, 128, 0, stream>>>(G2 + 256, G2, G2 + 384, G2b + 384, rowptr, csr, normv, 1.f, 0.f);
  gemm_bf16_kernel<ACT_LSIG, true, false, 1><<<dim3(GM,1), 64, 0, stream>>>(
      G2b, 512, 512, Wg + (size_t)546*1024, 1, bt6, 16, out, 16, nullptr, 0);
}